// Round 1
// baseline (118.577 us; speedup 1.0000x reference)
//
#include <hip/hip_runtime.h>
#include <math.h>

#define BB 8
#define NN 64
#define SS 128
#define DD 512
#define HH 8
#define DKK 64

// ---------------------------------------------------------------------------
// Kernel 1: fold Wk with sent_q:  wk_t[h][d] = sum_k Wk[d, h*64+k] * sent_q[h,k]
// (bk is softmax-shift-invariant -> skipped entirely)
// grid: HH blocks x DD threads
// ---------------------------------------------------------------------------
__global__ void precompute_wk(const float* __restrict__ Wk,
                              const float* __restrict__ sq,
                              float* __restrict__ wk_t) {
    const int d = threadIdx.x;   // 0..511
    const int h = blockIdx.x;    // 0..7
    const float4* wrow = (const float4*)(Wk + (size_t)d * DD + h * DKK);
    const float4* sqv  = (const float4*)(sq + h * DKK);
    float acc = 0.f;
#pragma unroll
    for (int k = 0; k < DKK / 4; ++k) {
        float4 w = wrow[k], q = sqv[k];
        acc += w.x * q.x + w.y * q.y + w.z * q.z + w.w * q.w;
    }
    wk_t[h * DD + d] = acc;
}

// ---------------------------------------------------------------------------
// Kernel 2: fused sentence attention. One block per (b,n) sentence.
// 512 threads = 8 waves.
//   Pass A: scores[h][s] = (x[s,:]·wk_eff[:,h]) * 1/8, masked
//   softmax over s per head (one wave per head)
//   Pass B: xbar[h][d] = sum_s attn[h][s] * x[s][d]
//   sent_repr/z: z[t] = bv[t] + xbar[h(t)] · Wv[:, t]
//   y[t] = bo[t] + z · Wo[:, t];  broadcast to all 128 token rows
// ---------------------------------------------------------------------------
__global__ __launch_bounds__(512, 4)
void sent_attn_kernel(const float* __restrict__ x,
                      const int* __restrict__ mask,
                      const float* __restrict__ wk_t,
                      const float* __restrict__ Wv,
                      const float* __restrict__ bv,
                      const float* __restrict__ Wo,
                      const float* __restrict__ bo,
                      float* __restrict__ out) {
    __shared__ float sc[HH][SS];    // scores -> attn (4 KB)
    __shared__ float xbar[HH][DD];  // weighted token average (16 KB)
    __shared__ float zsh[DD];       // concat sent_repr (2 KB)

    const int bid  = blockIdx.x;           // b*NN + n
    const int t    = threadIdx.x;          // 0..511
    const int wave = t >> 6;
    const int lane = t & 63;
    const float* xt = x + (size_t)bid * SS * DD;

    // ---- Pass A: sentence scores ----------------------------------------
    // lane owns dims d0..d0+7; preload the 8x8 wk slice into registers
    const int d0 = lane * 8;
    float4 wkA[HH], wkB[HH];
#pragma unroll
    for (int h = 0; h < HH; ++h) {
        wkA[h] = *(const float4*)(wk_t + h * DD + d0);
        wkB[h] = *(const float4*)(wk_t + h * DD + d0 + 4);
    }

    for (int s = wave; s < SS; s += 8) {
        const float* xr = xt + s * DD + d0;
        float4 xa = *(const float4*)xr;
        float4 xb = *(const float4*)(xr + 4);
        float p[HH];
#pragma unroll
        for (int h = 0; h < HH; ++h) {
            p[h] = xa.x * wkA[h].x + xa.y * wkA[h].y + xa.z * wkA[h].z + xa.w * wkA[h].w
                 + xb.x * wkB[h].x + xb.y * wkB[h].y + xb.z * wkB[h].z + xb.w * wkB[h].w;
        }
#pragma unroll
        for (int off = 32; off > 0; off >>= 1) {
#pragma unroll
            for (int h = 0; h < HH; ++h)
                p[h] += __shfl_down(p[h], off, 64);
        }
        if (lane == 0) {
            const int m = mask[bid * SS + s];
#pragma unroll
            for (int h = 0; h < HH; ++h)
                sc[h][s] = (m == 0) ? -1e9f : p[h] * 0.125f;
        }
    }
    __syncthreads();

    // ---- softmax over s, one wave per head --------------------------------
    {
        const int h = wave;
        float v0 = sc[h][lane], v1 = sc[h][lane + 64];
        float m = fmaxf(v0, v1);
#pragma unroll
        for (int off = 32; off > 0; off >>= 1)
            m = fmaxf(m, __shfl_xor(m, off, 64));
        float e0 = __expf(v0 - m);
        float e1 = __expf(v1 - m);
        float ssum = e0 + e1;
#pragma unroll
        for (int off = 32; off > 0; off >>= 1)
            ssum += __shfl_xor(ssum, off, 64);
        float inv = 1.0f / ssum;
        sc[h][lane]      = e0 * inv;
        sc[h][lane + 64] = e1 * inv;
    }
    __syncthreads();

    // ---- Pass B: xbar[h][d] = sum_s attn[h][s] * x[s][d] -----------------
    {
        float acc[HH];
#pragma unroll
        for (int h = 0; h < HH; ++h) acc[h] = 0.f;
#pragma unroll 4
        for (int s = 0; s < SS; ++s) {
            float xv = xt[(size_t)s * DD + t];   // coalesced across threads
#pragma unroll
            for (int h = 0; h < HH; ++h)
                acc[h] += sc[h][s] * xv;         // sc broadcast from LDS
        }
#pragma unroll
        for (int h = 0; h < HH; ++h) xbar[h][t] = acc[h];
    }
    __syncthreads();

    // ---- sent_repr: z[t] = bv[t] + xbar[h] · Wv[:, t] ---------------------
    {
        const int h = t >> 6;                    // head for this output col
        const float* wvp = Wv + t;               // column t, stride DD
        const float* xb  = &xbar[h][0];
        float a0 = 0.f, a1 = 0.f, a2 = 0.f, a3 = 0.f;
#pragma unroll 4
        for (int d = 0; d < DD; d += 4) {
            a0 += xb[d + 0] * wvp[(size_t)(d + 0) * DD];
            a1 += xb[d + 1] * wvp[(size_t)(d + 1) * DD];
            a2 += xb[d + 2] * wvp[(size_t)(d + 2) * DD];
            a3 += xb[d + 3] * wvp[(size_t)(d + 3) * DD];
        }
        zsh[t] = bv[t] + ((a0 + a1) + (a2 + a3));
    }
    __syncthreads();

    // ---- final projection + broadcast store -------------------------------
    {
        const float* wop = Wo + t;               // column t, stride DD
        float a0 = 0.f, a1 = 0.f, a2 = 0.f, a3 = 0.f;
#pragma unroll 4
        for (int d = 0; d < DD; d += 4) {
            a0 += zsh[d + 0] * wop[(size_t)(d + 0) * DD];
            a1 += zsh[d + 1] * wop[(size_t)(d + 1) * DD];
            a2 += zsh[d + 2] * wop[(size_t)(d + 2) * DD];
            a3 += zsh[d + 3] * wop[(size_t)(d + 3) * DD];
        }
        const float y = bo[t] + ((a0 + a1) + (a2 + a3));
        float* op = out + (size_t)bid * SS * DD + t;
#pragma unroll 4
        for (int s = 0; s < SS; ++s)
            op[(size_t)s * DD] = y;              // identical row for every token
    }
}

extern "C" void kernel_launch(void* const* d_in, const int* in_sizes, int n_in,
                              void* d_out, int out_size, void* d_ws, size_t ws_size,
                              hipStream_t stream) {
    const float* x    = (const float*)d_in[0];
    const int*   mask = (const int*)  d_in[1];
    // d_in[2]=Wq, d_in[3]=bq : dead code (token softmax over singleton axis)
    const float* Wk   = (const float*)d_in[4];
    // d_in[5]=bk : softmax-shift-invariant, skipped
    const float* Wv   = (const float*)d_in[6];
    const float* bv   = (const float*)d_in[7];
    const float* sq   = (const float*)d_in[8];
    const float* Wo   = (const float*)d_in[9];
    const float* bo   = (const float*)d_in[10];
    float* out  = (float*)d_out;
    float* wk_t = (float*)d_ws;   // HH*DD floats = 16 KB

    precompute_wk<<<HH, DD, 0, stream>>>(Wk, sq, wk_t);
    sent_attn_kernel<<<BB * NN, DD, 0, stream>>>(x, mask, wk_t, Wv, bv, Wo, bo, out);
}